// Round 1
// baseline (28.260 us; speedup 1.0000x reference)
//
#include <hip/hip_runtime.h>
#include <math.h>

#ifndef __has_builtin
#define __has_builtin(x) 0
#endif

__device__ __forceinline__ float fexp2(float v) {
#if __has_builtin(__builtin_amdgcn_exp2f)
  return __builtin_amdgcn_exp2f(v);
#else
  return exp2f(v);
#endif
}

constexpr int Bc  = 8;
constexpr int Nc  = 512;
constexpr int Mc  = 2048;
constexpr int CIN = 8;
constexpr int Cc  = 9;     // 1 + CIN
constexpr int Oc  = 64;

constexpr int THREADS = 256;
constexpr int LN = 16;                      // n-slices (lanes cooperating per m)
constexpr int MT = 2;                       // m per thread
constexpr int MTILE = (THREADS / LN) * MT;  // 32 m per block
// grid = Bc * (Mc / MTILE) = 8 * 64 = 512 blocks -> 2 blocks/CU

__global__ __launch_bounds__(THREADS, 2) void convdeepset(
    const float* __restrict__ xg, const float* __restrict__ yg,
    const float* __restrict__ tg, const float* __restrict__ sg,
    const float* __restrict__ Wg, const float* __restrict__ bg,
    float* __restrict__ outg)
{
  __shared__ float sx[Nc];
  __shared__ float sy[Nc][CIN];
  __shared__ float sW[Cc][Oc];
  __shared__ float sb[Oc];

  const int tid = threadIdx.x;
  const int bx  = blockIdx.x;
  const int b   = bx >> 6;            // 64 tiles per batch
  const int m0  = (bx & 63) * MTILE;

  // ---- stage inputs to LDS ----
  for (int i = tid; i < Nc; i += THREADS) sx[i] = xg[b * Nc + i];
  {
    const float4* ys = reinterpret_cast<const float4*>(yg + b * Nc * CIN);
    float4* yd = reinterpret_cast<float4*>(&sy[0][0]);
    for (int i = tid; i < Nc * CIN / 4; i += THREADS) yd[i] = ys[i];
  }
  for (int i = tid; i < Cc * Oc; i += THREADS) (&sW[0][0])[i] = Wg[i];
  if (tid < Oc) sb[tid] = bg[tid];

  // per-channel exp2 coefficient: wt = exp(-0.5 d / s_c^2) = exp2(k_c * d)
  float kk[Cc];
  bool uni = true;
  {
    const float s0 = sg[0];
    #pragma unroll
    for (int c = 0; c < Cc; ++c) {
      const float s = sg[c];
      kk[c] = -0.72134752044448170f * __expf(-2.0f * s);  // -0.5*log2(e)*e^{-2 sigma}
      uni = uni && (s == s0);
    }
  }
  __syncthreads();

  const int ns = tid & (LN - 1);  // n-slice 0..15
  const int ml = tid >> 4;        // m-group 0..15

  float tv[MT];
  #pragma unroll
  for (int j = 0; j < MT; ++j) tv[j] = tg[b * Mc + m0 + ml * MT + j];

  float acc[MT][Cc];
  #pragma unroll
  for (int j = 0; j < MT; ++j)
    #pragma unroll
    for (int c = 0; c < Cc; ++c) acc[j][c] = 0.0f;

  const float4* sy4 = reinterpret_cast<const float4*>(&sy[0][0]);

  if (uni) {
    // all channels share one scale: one exp per (n,m) pair
    const float q = sqrtf(-kk[0]);
    float tq[MT];
    #pragma unroll
    for (int j = 0; j < MT; ++j) tq[j] = tv[j] * q;

    for (int i = 0; i < Nc / LN; ++i) {
      const int n = (i << 4) + ns;
      const float xq = sx[n] * q;
      const float4 ya = sy4[2 * n];
      const float4 yb = sy4[2 * n + 1];
      #pragma unroll
      for (int j = 0; j < MT; ++j) {
        const float dq = xq - tq[j];
        const float w = fexp2(-dq * dq);
        acc[j][0] += w;
        acc[j][1] += ya.x * w; acc[j][2] += ya.y * w;
        acc[j][3] += ya.z * w; acc[j][4] += ya.w * w;
        acc[j][5] += yb.x * w; acc[j][6] += yb.y * w;
        acc[j][7] += yb.z * w; acc[j][8] += yb.w * w;
      }
    }
  } else {
    // general per-channel scales
    for (int i = 0; i < Nc / LN; ++i) {
      const int n = (i << 4) + ns;
      const float xv = sx[n];
      const float4 ya = sy4[2 * n];
      const float4 yb = sy4[2 * n + 1];
      #pragma unroll
      for (int j = 0; j < MT; ++j) {
        const float diff = xv - tv[j];
        const float d2 = diff * diff;
        float w[Cc];
        #pragma unroll
        for (int c = 0; c < Cc; ++c) w[c] = fexp2(d2 * kk[c]);
        acc[j][0] += w[0];
        acc[j][1] += ya.x * w[1]; acc[j][2] += ya.y * w[2];
        acc[j][3] += ya.z * w[3]; acc[j][4] += ya.w * w[4];
        acc[j][5] += yb.x * w[5]; acc[j][6] += yb.y * w[6];
        acc[j][7] += yb.z * w[7]; acc[j][8] += yb.w * w[8];
      }
    }
  }

  // butterfly reduce across the 16 n-slice lanes (all lanes end with full sums)
  #pragma unroll
  for (int off = 1; off < LN; off <<= 1)
    #pragma unroll
    for (int j = 0; j < MT; ++j)
      #pragma unroll
      for (int c = 0; c < Cc; ++c)
        acc[j][c] += __shfl_xor(acc[j][c], off, 64);

  // fused epilogue: h = [density, conv/density], out = h @ W + b
  const int o = ns * 4;  // each lane produces 4 of the 64 outputs per m
  float4 wr[Cc];
  #pragma unroll
  for (int c = 0; c < Cc; ++c)
    wr[c] = *reinterpret_cast<const float4*>(&sW[c][o]);
  const float4 bv = *reinterpret_cast<const float4*>(&sb[o]);

  #pragma unroll
  for (int j = 0; j < MT; ++j) {
    const float dens = acc[j][0];
    const float inv = 1.0f / (dens + 1e-8f);
    float4 r = bv;
    r.x += dens * wr[0].x; r.y += dens * wr[0].y;
    r.z += dens * wr[0].z; r.w += dens * wr[0].w;
    #pragma unroll
    for (int c = 1; c < Cc; ++c) {
      const float h = acc[j][c] * inv;
      r.x += h * wr[c].x; r.y += h * wr[c].y;
      r.z += h * wr[c].z; r.w += h * wr[c].w;
    }
    const int m = m0 + ml * MT + j;
    reinterpret_cast<float4*>(outg)[((b * Mc + m) * Oc + o) >> 2] = r;
  }
}

extern "C" void kernel_launch(void* const* d_in, const int* in_sizes, int n_in,
                              void* d_out, int out_size, void* d_ws, size_t ws_size,
                              hipStream_t stream) {
  const float* x  = (const float*)d_in[0];
  const float* y  = (const float*)d_in[1];
  const float* t  = (const float*)d_in[2];
  const float* s  = (const float*)d_in[3];
  const float* W  = (const float*)d_in[4];
  const float* bb = (const float*)d_in[5];
  float* out = (float*)d_out;

  dim3 grid(Bc * (Mc / MTILE));
  convdeepset<<<grid, THREADS, 0, stream>>>(x, y, t, s, W, bb, out);
}

// Round 2
// 18.228 us; speedup vs baseline: 1.5503x; 1.5503x over previous
//
#include <hip/hip_runtime.h>
#include <math.h>

#ifndef __has_builtin
#define __has_builtin(x) 0
#endif

__device__ __forceinline__ float fexp2(float v) {
#if __has_builtin(__builtin_amdgcn_exp2f)
  return __builtin_amdgcn_exp2f(v);
#else
  return exp2f(v);
#endif
}

constexpr int Bc  = 8;
constexpr int Nc  = 512;
constexpr int Mc  = 2048;
constexpr int CIN = 8;
constexpr int Cc  = 9;     // 1 + CIN
constexpr int Oc  = 64;
constexpr int SN  = 8;     // n-slices across blocks
constexpr int NS  = Nc / SN;  // 64 n per slice

// ---------------- K1: partial channel sums over an n-slice ----------------
// Each lane owns ONE output row m. All x/y accesses are wave-uniform ->
// scalar loads (s_load) on the K$/SALU pipe; inner loop is pure VALU:
// sub, mul, exp (neg mod), 9 fmac with SGPR operands. No LDS, no shuffles.
// grid = Bc * (Mc/256) * SN = 8*8*8 = 512 blocks -> 2 blocks/CU.
__global__ __launch_bounds__(256, 2) void k1_partial(
    const float* __restrict__ xg, const float* __restrict__ yg,
    const float* __restrict__ tg, const float* __restrict__ sg,
    float* __restrict__ ws)
{
  const int bx = blockIdx.x;
  const int sl = bx & (SN - 1);
  const int mt = (bx >> 3) & 7;
  const int b  = bx >> 6;
  const int m  = mt * 256 + threadIdx.x;

  // per-channel exp2 coefficient: exp(-0.5 d / s_c^2) = exp2(kk_c * d)
  float kk[Cc];
  bool uni = true;
  const float s0 = sg[0];
  #pragma unroll
  for (int c = 0; c < Cc; ++c) {
    const float s = sg[c];
    kk[c] = -0.72134752044448170f * __expf(-2.0f * s);  // -0.5*log2(e)*e^{-2 sigma}
    uni = uni && (s == s0);
  }

  const float tm = tg[b * Mc + m];
  const float* __restrict__ xb = xg + b * Nc + sl * NS;
  const float* __restrict__ yb = yg + (size_t)(b * Nc + sl * NS) * CIN;

  float acc[Cc];
  #pragma unroll
  for (int c = 0; c < Cc; ++c) acc[c] = 0.0f;

  if (uni) {
    const float q  = sqrtf(-kk[0]);
    const float tq = tm * q;
    #pragma unroll 4
    for (int n = 0; n < NS; ++n) {
      const float dq = xb[n] * q - tq;
      const float w  = fexp2(-dq * dq);
      acc[0] += w;
      #pragma unroll
      for (int c = 1; c < Cc; ++c) acc[c] += yb[n * CIN + (c - 1)] * w;
    }
  } else {
    #pragma unroll 4
    for (int n = 0; n < NS; ++n) {
      const float d  = xb[n] - tm;
      const float d2 = d * d;
      acc[0] += fexp2(d2 * kk[0]);
      #pragma unroll
      for (int c = 1; c < Cc; ++c) acc[c] += yb[n * CIN + (c - 1)] * fexp2(d2 * kk[c]);
    }
  }

  // ws layout [sl][b][c][m]: per-(sl,b,c) a contiguous run of m -> coalesced
  #pragma unroll
  for (int c = 0; c < Cc; ++c)
    ws[((size_t)(sl * Bc + b) * Cc + c) * Mc + m] = acc[c];
}

// ---------------- K2: reduce slices + density div + h @ W + bias ----------
// grid = Bc * (Mc/64) = 256 blocks; block handles 64 m's.
__global__ __launch_bounds__(256, 2) void k2_final(
    const float* __restrict__ ws, const float* __restrict__ Wg,
    const float* __restrict__ bg, float* __restrict__ outg)
{
  __shared__ float part[SN][Cc][64];  // 18 KB
  __shared__ float hh[Cc][64];
  __shared__ float sW[Cc][Oc];
  __shared__ float sb2[Oc];

  const int tid = threadIdx.x;
  const int bx  = blockIdx.x;
  const int b   = bx >> 5;
  const int m0  = (bx & 31) * 64;

  for (int i = tid; i < SN * Cc * 64; i += 256) {
    const int sl = i / (Cc * 64);
    const int r  = i - sl * (Cc * 64);
    const int c  = r >> 6;
    const int mm = r & 63;
    part[sl][c][mm] = ws[((size_t)(sl * Bc + b) * Cc + c) * Mc + m0 + mm];
  }
  for (int i = tid; i < Cc * Oc; i += 256) (&sW[0][0])[i] = Wg[i];
  if (tid < Oc) sb2[tid] = bg[tid];
  __syncthreads();

  {
    const int mm = tid & 63;
    for (int c = tid >> 6; c < Cc; c += 4) {   // cg covers {0,4,8},{1,5},{2,6},{3,7}
      float s = part[0][c][mm];
      #pragma unroll
      for (int sl = 1; sl < SN; ++sl) s += part[sl][c][mm];
      hh[c][mm] = s;
    }
  }
  __syncthreads();

  const int oq  = tid & 15;   // o-quad 0..15
  const int mm0 = tid >> 4;   // 0..15
  float4 wr[Cc];
  #pragma unroll
  for (int c = 0; c < Cc; ++c)
    wr[c] = *reinterpret_cast<const float4*>(&sW[c][oq * 4]);
  const float4 bv = *reinterpret_cast<const float4*>(&sb2[oq * 4]);

  #pragma unroll
  for (int k = 0; k < 4; ++k) {
    const int mm = mm0 + k * 16;
    const float dens = hh[0][mm];              // broadcast within 16-lane group
    const float inv  = 1.0f / (dens + 1e-8f);
    float4 r = bv;
    r.x += dens * wr[0].x; r.y += dens * wr[0].y;
    r.z += dens * wr[0].z; r.w += dens * wr[0].w;
    #pragma unroll
    for (int c = 1; c < Cc; ++c) {
      const float h = hh[c][mm] * inv;
      r.x += h * wr[c].x; r.y += h * wr[c].y;
      r.z += h * wr[c].z; r.w += h * wr[c].w;
    }
    // lanes: oq fastest, mm next -> a wave stores 1 KB contiguous
    reinterpret_cast<float4*>(outg)[((size_t)(b * Mc + m0 + mm) * Oc + oq * 4) >> 2] = r;
  }
}

extern "C" void kernel_launch(void* const* d_in, const int* in_sizes, int n_in,
                              void* d_out, int out_size, void* d_ws, size_t ws_size,
                              hipStream_t stream) {
  const float* x  = (const float*)d_in[0];
  const float* y  = (const float*)d_in[1];
  const float* t  = (const float*)d_in[2];
  const float* s  = (const float*)d_in[3];
  const float* W  = (const float*)d_in[4];
  const float* bb = (const float*)d_in[5];
  float* out = (float*)d_out;
  float* ws  = (float*)d_ws;   // needs SN*Bc*Cc*Mc*4 = 4.7 MB (<< ws_size)

  k1_partial<<<dim3(Bc * (Mc / 256) * SN), 256, 0, stream>>>(x, y, t, s, ws);
  k2_final<<<dim3(Bc * (Mc / 64)), 256, 0, stream>>>(ws, W, bb, out);
}